// Round 6
// baseline (8051.861 us; speedup 1.0000x reference)
//
#include <hip/hip_runtime.h>

constexpr int D_  = 1024;  // embedding dim
constexpr int E_  = 64;    // experts
constexpr int N_  = 1024;  // B*S tokens
constexpr int TG  = 32;    // tokens per pass
constexpr int CS  = 32;    // column slices (blocks per expert)
constexpr int CPB = D_ / CS;   // 32 cols per block (1 col per thread)
constexpr int KG  = 8;     // k-groups (tid>>5)
constexpr int KR  = D_ / KG;   // 128 k-rows per group
constexpr int DC  = 8;     // w rows per register buffer
constexpr int NC  = KR / DC;   // 16 chunks

// One block = (col-slice cs, expert e). 256 threads = 8 k-groups x 32 cols.
// Barrier-free K loop: w double-buffered in NAMED SCALARS (spill-proof),
// trans streamed nontemporally from HBM exactly once, x read via L1/L2
// broadcast. Barriers only in bucketing + reduce epilogue.
__global__ __launch_bounds__(256, 4) void fused_moe_kernel(
    const float* __restrict__ x, const int* __restrict__ urls,
    const float* __restrict__ trans, const float* __restrict__ bias,
    float* __restrict__ out) {
  __shared__ int toksL[N_];         // 4 KB (zero-padded: tail quads read tok 0)
  __shared__ float red[KG][8][33];  // 8.25 KB, pad 33: conflict-free
  __shared__ int cntS;

  const int tid = threadIdx.x;
  const int cs  = blockIdx.x;
  const int e   = blockIdx.y;
  const int kg  = tid >> 5;   // 0..7
  const int ct  = tid & 31;   // 0..31
  const int c0  = cs * CPB;

  // ---- in-block bucketing ----
  for (int i = tid; i < N_; i += 256) toksL[i] = 0;
  if (tid == 0) cntS = 0;
  __syncthreads();
  for (int i = tid; i < N_; i += 256) {
    if (urls[i] == e) { int p = atomicAdd(&cntS, 1); toksL[p] = i; }
  }
  __syncthreads();
  const int Ttot = cntS;

  const float* __restrict__ tr = trans + (size_t)e * D_ * D_ + c0 + ct;
  const int kbase0 = kg * KR;

  for (int beg = 0; beg < Ttot; beg += TG) {
    const int T     = (Ttot - beg < TG) ? (Ttot - beg) : TG;
    const int nQuad = (T + 3) >> 2;

    float acc[TG];
#pragma unroll
    for (int t = 0; t < TG; ++t) acc[t] = 0.f;

    float w00, w01, w02, w03, w04, w05, w06, w07;
    float w10, w11, w12, w13, w14, w15, w16, w17;

#define LOADW(P, c) do {                                          \
    const float* _p = tr + (size_t)(kbase0 + (c) * DC) * D_;      \
    P##0 = __builtin_nontemporal_load(_p);                        \
    P##1 = __builtin_nontemporal_load(_p + (size_t)D_);           \
    P##2 = __builtin_nontemporal_load(_p + 2 * (size_t)D_);       \
    P##3 = __builtin_nontemporal_load(_p + 3 * (size_t)D_);       \
    P##4 = __builtin_nontemporal_load(_p + 4 * (size_t)D_);       \
    P##5 = __builtin_nontemporal_load(_p + 5 * (size_t)D_);       \
    P##6 = __builtin_nontemporal_load(_p + 6 * (size_t)D_);       \
    P##7 = __builtin_nontemporal_load(_p + 7 * (size_t)D_);       \
  } while (0)

#define COMPW(P, c) do {                                                     \
    const int _kb = kbase0 + (c) * DC;                                       \
    _Pragma("unroll")                                                        \
    for (int q = 0; q < TG / 4; ++q) {                                       \
      if (q < nQuad) { /* uniform: skip empty token quads */                 \
        _Pragma("unroll")                                                    \
        for (int j = 0; j < 4; ++j) {                                        \
          const int _tk = toksL[beg + q * 4 + j];                            \
          const float* _xp = x + (size_t)_tk * D_ + _kb;                     \
          const float4 _a0 = *(const float4*)(_xp);                          \
          const float4 _a1 = *(const float4*)(_xp + 4);                      \
          float _s = acc[q * 4 + j];                                         \
          _s += _a0.x * P##0 + _a0.y * P##1 + _a0.z * P##2 + _a0.w * P##3;   \
          _s += _a1.x * P##4 + _a1.y * P##5 + _a1.z * P##6 + _a1.w * P##7;   \
          acc[q * 4 + j] = _s;                                               \
        }                                                                    \
      }                                                                      \
    }                                                                        \
  } while (0)

    // software-pipelined, barrier-free: chunk c+1's loads in flight under
    // chunk c's compute; no vmcnt(0) drains anywhere in this loop
    LOADW(w0, 0);
#pragma unroll
    for (int c = 0; c < NC; c += 2) {
      LOADW(w1, c + 1);
      COMPW(w0, c);
      if (c + 2 < NC) LOADW(w0, c + 2);
      COMPW(w1, c + 1);
    }
#undef LOADW
#undef COMPW

    // ---- reduce across k-groups + bias + tanh + store (4 rounds x 8 tokens) ----
    const int tt_r = tid >> 5;  // token-in-round 0..7
    const int ct_r = tid & 31;
#pragma unroll
    for (int r = 0; r < 4; ++r) {
      __syncthreads();  // red free (prev round's reads / prev pass done)
#pragma unroll
      for (int tt = 0; tt < 8; ++tt)
        red[kg][tt][ct] = acc[r * 8 + tt];
      __syncthreads();
      const int slot = r * 8 + tt_r;
      if (slot < T) {
        float s = 0.f;
#pragma unroll
        for (int g = 0; g < KG; ++g) s += red[g][tt_r][ct_r];
        const int tok = toksL[beg + slot];
        const float b = bias[(size_t)e * D_ + c0 + ct_r];  // urls[tok] == e
        out[(size_t)tok * D_ + c0 + ct_r] = tanhf(s + b);
      }
    }
  }
}

extern "C" void kernel_launch(void* const* d_in, const int* in_sizes, int n_in,
                              void* d_out, int out_size, void* d_ws, size_t ws_size,
                              hipStream_t stream) {
  const float* x     = (const float*)d_in[0];
  const int*   urls  = (const int*)d_in[1];
  const float* trans = (const float*)d_in[2];
  const float* bias  = (const float*)d_in[3];
  float* out = (float*)d_out;

  dim3 grid(CS, E_);
  fused_moe_kernel<<<grid, 256, 0, stream>>>(x, urls, trans, bias, out);
}

// Round 8
// 240.941 us; speedup vs baseline: 33.4184x; 33.4184x over previous
//
#include <hip/hip_runtime.h>

constexpr int D_  = 1024;  // embedding dim
constexpr int E_  = 64;    // experts
constexpr int N_  = 1024;  // B*S tokens
constexpr int TG  = 32;    // tokens per pass (max bucket slice)
constexpr int CS  = 32;    // column slices (blocks per expert)
constexpr int CPB = 32;    // cols per block (1 col per thread)
constexpr int KG  = 4;     // k-groups = waves per block
constexpr int KR  = D_ / KG;   // 256 k-rows per group
constexpr int TPT = 16;    // max tokens per thread (per half)
constexpr int DC  = 8;     // w rows per register buffer
constexpr int NCH = KR / DC;   // 32 chunks

// Block = (col-slice cs, expert e). 256 threads = 32 cols x 2 token-halves x
// 4 k-groups (1 per wave). Per thread: acc[16] + 16 named w scalars + small
// x pipeline ~= 60 VGPR -- fits even a 64-VGPR occupancy clamp (the round-5/6
// spill killer). K-loop is barrier-free and a RUNTIME loop (no giant unrolled
// region -> no load-hoisting pressure blowup). w-load address is identical for
// all 64 lanes' rows (2-way ts broadcast): one 128 B line per load, trans
// streamed from HBM exactly once. x served from L1/L2 broadcast.
__global__ __launch_bounds__(256, 4) void fused_moe_kernel(
    const float* __restrict__ x, const int* __restrict__ urls,
    const float* __restrict__ trans, const float* __restrict__ bias,
    float* __restrict__ out) {
  __shared__ int toksL[N_];              // 4 KB (zero-padded tail)
  __shared__ float red[KG][TG][CPB];     // 16 KB, ct-consecutive: conflict-free
  __shared__ int cntS;

  const int tid = threadIdx.x;
  const int ct  = tid & 31;        // column within slice
  const int ts  = (tid >> 5) & 1;  // token half
  const int kg  = tid >> 6;        // k-group == wave id
  const int cs  = blockIdx.x;
  const int e   = blockIdx.y;
  const int c0  = cs * CPB;

  // ---- in-block bucketing ----
  for (int i = tid; i < N_; i += 256) toksL[i] = 0;
  if (tid == 0) cntS = 0;
  __syncthreads();
  for (int i = tid; i < N_; i += 256)
    if (urls[i] == e) { int p = atomicAdd(&cntS, 1); toksL[p] = i; }
  __syncthreads();
  const int Ttot = cntS;

  const float* __restrict__ tr = trans + (size_t)e * D_ * D_ + c0 + ct;
  const int kb0 = kg * KR;
  const float bv = bias[(size_t)e * D_ + c0 + ct];  // urls[tok]==e in bucket

  for (int beg = 0; beg < Ttot; beg += TG) {
    const int T  = (Ttot - beg < TG) ? (Ttot - beg) : TG;
    const int h  = (T + 1) >> 1;            // balanced split point
    const int Tts = ts ? (T - h) : h;       // tokens in my half
    const int nQ  = (Tts + 3) >> 2;
    const int tbase = beg + (ts ? h : 0);

    float acc[TPT];
#pragma unroll
    for (int t = 0; t < TPT; ++t) acc[t] = 0.f;

    float w00, w01, w02, w03, w04, w05, w06, w07;
    float w10, w11, w12, w13, w14, w15, w16, w17;

#define LOADW(P, c) do {                                              \
    const float* _p = tr + (size_t)(kb0 + (c) * DC) * D_;             \
    P##0 = __builtin_nontemporal_load(_p);                            \
    P##1 = __builtin_nontemporal_load(_p + (size_t)D_);               \
    P##2 = __builtin_nontemporal_load(_p + 2 * (size_t)D_);           \
    P##3 = __builtin_nontemporal_load(_p + 3 * (size_t)D_);           \
    P##4 = __builtin_nontemporal_load(_p + 4 * (size_t)D_);           \
    P##5 = __builtin_nontemporal_load(_p + 5 * (size_t)D_);           \
    P##6 = __builtin_nontemporal_load(_p + 6 * (size_t)D_);           \
    P##7 = __builtin_nontemporal_load(_p + 7 * (size_t)D_);           \
  } while (0)

#define COMP(P, c) do {                                                      \
    const int _kb = kb0 + (c) * DC;                                          \
    _Pragma("unroll")                                                        \
    for (int q = 0; q < TPT / 4; ++q) {                                      \
      if (q < nQ) { /* guard fences load-hoisting to <=8 loads/region */     \
        _Pragma("unroll")                                                    \
        for (int j = 0; j < 4; ++j) {                                        \
          const int _tk = toksL[tbase + q * 4 + j];                          \
          const float* _xp = x + ((size_t)_tk << 10) + _kb;                  \
          const float4 _a0 = *(const float4*)(_xp);                          \
          const float4 _a1 = *(const float4*)(_xp + 4);                      \
          float _s = acc[q * 4 + j];                                         \
          _s += _a0.x * P##0 + _a0.y * P##1 + _a0.z * P##2 + _a0.w * P##3;   \
          _s += _a1.x * P##4 + _a1.y * P##5 + _a1.z * P##6 + _a1.w * P##7;   \
          acc[q * 4 + j] = _s;                                               \
        }                                                                    \
      }                                                                      \
    }                                                                        \
  } while (0)

    // barrier-free, software-pipelined K loop (runtime trip count: the body
    // stays one small scheduling region -> no register-pressure blowup)
    LOADW(w0, 0);
    for (int c = 0; c < NCH; c += 2) {
      LOADW(w1, c + 1);
      COMP(w0, c);
      if (c + 2 < NCH) LOADW(w0, c + 2);
      COMP(w1, c + 1);
    }
#undef LOADW
#undef COMP

    // ---- cross-wave k-reduce + bias + tanh + store ----
    __syncthreads();  // prev pass's red reads complete
#pragma unroll
    for (int t = 0; t < TPT; ++t) {
      if (t < Tts)  // guard: tail-quad partials beyond my half are DISCARDED
        red[kg][(ts ? h : 0) + t][ct] = acc[t];
    }
    __syncthreads();

    const int s8 = tid >> 5;  // 0..7
#pragma unroll
    for (int r = 0; r < 4; ++r) {
      const int s = r * 8 + s8;
      if (s < T) {
        const float sum = red[0][s][ct] + red[1][s][ct] +
                          red[2][s][ct] + red[3][s][ct];
        const int tok = toksL[beg + s];
        out[((size_t)tok << 10) + c0 + ct] = tanhf(sum + bv);
      }
    }
  }
}

extern "C" void kernel_launch(void* const* d_in, const int* in_sizes, int n_in,
                              void* d_out, int out_size, void* d_ws, size_t ws_size,
                              hipStream_t stream) {
  const float* x     = (const float*)d_in[0];
  const int*   urls  = (const int*)d_in[1];
  const float* trans = (const float*)d_in[2];
  const float* bias  = (const float*)d_in[3];
  float* out = (float*)d_out;

  dim3 grid(CS, E_);
  fused_moe_kernel<<<grid, 256, 0, stream>>>(x, urls, trans, bias, out);
}

// Round 9
// 205.396 us; speedup vs baseline: 39.2017x; 1.1731x over previous
//
#include <hip/hip_runtime.h>

constexpr int D_  = 1024;  // embedding dim
constexpr int E_  = 64;    // experts
constexpr int N_  = 1024;  // B*S tokens
constexpr int TG  = 32;    // tokens per pass (max bucket slice)
constexpr int CS  = 16;    // column slices (blocks per expert)
constexpr int CPB = 64;    // cols per block (1 col per lane, 64-lane wave)
constexpr int KG  = 4;     // k-groups = waves per block
constexpr int KR  = D_ / KG;   // 256 k-rows per wave
constexpr int DC  = 8;     // w rows per register bank
constexpr int NCH = KR / DC;   // 32 chunks

// Block = (col-slice cs, expert e). 256 threads = 4 waves (one k-group each);
// all 64 lanes of a wave = 64 consecutive cols -> each w-load is one full
// 256 B transaction. acc[32] covers the whole bucket (no token split).
// K-loop: barrier-free, runtime trip count, double-buffered w in named
// scalars (dword rows), plain cached loads (trans is L3-resident across
// replays; first touch streams HBM once). x read as uniform float4 broadcast
// (L1/L2-hot, 4 MB total). Per-quad guards fence load-hoisting (<=8
// loads/region) so register pressure stays ~100 VGPR: no spills.
__global__ __launch_bounds__(256, 4) void fused_moe_kernel(
    const float* __restrict__ x, const int* __restrict__ urls,
    const float* __restrict__ trans, const float* __restrict__ bias,
    float* __restrict__ out) {
  __shared__ int toksL[N_ + TG];        // 4.1 KB, zero-padded tail
  __shared__ float red[KG][TG][CPB];    // 32 KB, lane-consecutive: conflict-free
  __shared__ int cntS;

  const int tid  = threadIdx.x;
  const int lane = tid & 63;   // column within slice
  const int kg   = tid >> 6;   // k-group == wave id
  const int cs   = blockIdx.x;
  const int e    = blockIdx.y;
  const int c0   = cs * CPB;

  // ---- in-block bucketing ----
  for (int i = tid; i < N_ + TG; i += 256) toksL[i] = 0;
  if (tid == 0) cntS = 0;
  __syncthreads();
  for (int i = tid; i < N_; i += 256)
    if (urls[i] == e) { int p = atomicAdd(&cntS, 1); toksL[p] = i; }
  __syncthreads();
  const int Ttot = cntS;

  const float* __restrict__ tr = trans + (size_t)e * D_ * D_ + c0 + lane;
  const int kb0 = kg * KR;
  const float bv = bias[(size_t)e * D_ + c0 + lane];  // urls[tok]==e in bucket

  for (int beg = 0; beg < Ttot; beg += TG) {
    const int T  = (Ttot - beg < TG) ? (Ttot - beg) : TG;
    const int nQ = (T + 3) >> 2;

    float acc[TG];
#pragma unroll
    for (int t = 0; t < TG; ++t) acc[t] = 0.f;

    float w00, w01, w02, w03, w04, w05, w06, w07;
    float w10, w11, w12, w13, w14, w15, w16, w17;

#define LOADW(P, c) do {                                  \
    const float* _p = tr + (size_t)(kb0 + (c) * DC) * D_; \
    P##0 = _p[0];                                         \
    P##1 = _p[D_];                                        \
    P##2 = _p[2 * (size_t)D_];                            \
    P##3 = _p[3 * (size_t)D_];                            \
    P##4 = _p[4 * (size_t)D_];                            \
    P##5 = _p[5 * (size_t)D_];                            \
    P##6 = _p[6 * (size_t)D_];                            \
    P##7 = _p[7 * (size_t)D_];                            \
  } while (0)

#define COMP(P, c) do {                                                      \
    const int _kb = kb0 + (c) * DC;                                          \
    _Pragma("unroll")                                                        \
    for (int q = 0; q < TG / 4; ++q) {                                       \
      if (q < nQ) { /* guard fences load-hoisting to <=8 loads/region */     \
        _Pragma("unroll")                                                    \
        for (int j = 0; j < 4; ++j) {                                        \
          const int _tk = toksL[beg + q * 4 + j];                            \
          const float* _xp = x + ((size_t)_tk << 10) + _kb;                  \
          const float4 _a0 = *(const float4*)(_xp);                          \
          const float4 _a1 = *(const float4*)(_xp + 4);                      \
          float _s = acc[q * 4 + j];                                         \
          _s += _a0.x * P##0 + _a0.y * P##1 + _a0.z * P##2 + _a0.w * P##3;   \
          _s += _a1.x * P##4 + _a1.y * P##5 + _a1.z * P##6 + _a1.w * P##7;   \
          acc[q * 4 + j] = _s;                                               \
        }                                                                    \
      }                                                                      \
    }                                                                        \
  } while (0)

    // barrier-free, software-pipelined K loop (runtime trip count keeps each
    // scheduling region small -> no register-pressure blowup, no spills)
    LOADW(w0, 0);
    for (int c = 0; c < NCH; c += 2) {
      LOADW(w1, c + 1);
      COMP(w0, c);
      if (c + 2 < NCH) LOADW(w0, c + 2);
      COMP(w1, c + 1);
    }
#undef LOADW
#undef COMP

    // ---- cross-wave k-reduce + bias + tanh + store ----
    __syncthreads();  // prev pass's red reads complete
#pragma unroll
    for (int t = 0; t < TG; ++t) {
      if (t < T) red[kg][t][lane] = acc[t];
    }
    __syncthreads();

    const int s4 = tid >> 6;  // token-slot offset 0..3
#pragma unroll
    for (int r = 0; r < TG / 4; ++r) {
      const int s = r * 4 + s4;
      if (s < T) {
        const float sum = red[0][s][lane] + red[1][s][lane] +
                          red[2][s][lane] + red[3][s][lane];
        const int tok = toksL[beg + s];
        out[((size_t)tok << 10) + c0 + lane] = tanhf(sum + bv);
      }
    }
  }
}

extern "C" void kernel_launch(void* const* d_in, const int* in_sizes, int n_in,
                              void* d_out, int out_size, void* d_ws, size_t ws_size,
                              hipStream_t stream) {
  const float* x     = (const float*)d_in[0];
  const int*   urls  = (const int*)d_in[1];
  const float* trans = (const float*)d_in[2];
  const float* bias  = (const float*)d_in[3];
  float* out = (float*)d_out;

  dim3 grid(CS, E_);
  fused_moe_kernel<<<grid, 256, 0, stream>>>(x, urls, trans, bias, out);
}

// Round 10
// 122.829 us; speedup vs baseline: 65.5536x; 1.6722x over previous
//
#include <hip/hip_runtime.h>
#include <stdint.h>

constexpr int D_  = 1024;  // embedding dim
constexpr int E_  = 64;    // experts
constexpr int N_  = 1024;  // B*S tokens
constexpr int TG  = 32;    // tokens per pass (max bucket slice)
constexpr int CS  = 16;    // column slices (blocks per expert)
constexpr int CPB = 64;    // cols per block (1 col per lane)
constexpr int BK  = 32;    // k-rows staged per step
constexpr int NS  = D_ / BK;   // 32 steps

// direct global->LDS staging: no register consumer, so no vmcnt-ordering
// poison -- the only drain is the per-step barrier, hidden under compute.
#define GLDS16(g, l)                                                  \
  __builtin_amdgcn_global_load_lds(                                   \
      (const __attribute__((address_space(1))) void*)(g),             \
      (__attribute__((address_space(3))) void*)(l), 16, 0, 0)

// Block = (col-slice cs, expert e). 4 waves = 4 token-quarters; each wave
// computes ALL 1024 k for its 8 tokens (no cross-wave reduce). Per K-step:
// stage next W-tile (32x64) + x-tile (32 tok x 32 k) via global_load_lds
// (double-buffered), compute from LDS: w lane-consecutive b32 (conflict-free),
// x wave-uniform b128 broadcast. One vmcnt drain per step at the barrier.
__global__ __launch_bounds__(256, 4) void fused_moe_kernel(
    const float* __restrict__ x, const int* __restrict__ urls,
    const float* __restrict__ trans, const float* __restrict__ bias,
    float* __restrict__ out) {
  __shared__ __align__(16) float wl[2][BK * CPB];  // 2 x 8 KB
  __shared__ __align__(16) float xs[2][TG * BK];   // 2 x 4 KB
  __shared__ int toksL[N_ + TG];                   // 4.1 KB zero-padded
  __shared__ int cntS;

  const int tid  = threadIdx.x;
  const int lane = tid & 63;
  const int wv   = tid >> 6;   // wave id = token quarter
  const int cs   = blockIdx.x;
  const int e    = blockIdx.y;
  const int c0   = cs * CPB;

  // ---- in-block bucketing ----
  for (int i = tid; i < N_ + TG; i += 256) toksL[i] = 0;
  if (tid == 0) cntS = 0;
  __syncthreads();
  for (int i = tid; i < N_; i += 256)
    if (urls[i] == e) { int p = atomicAdd(&cntS, 1); toksL[p] = i; }
  __syncthreads();
  const int Ttot = cntS;
  if (Ttot == 0) return;  // uniform

  const float* __restrict__ tr = trans + (size_t)e * D_ * D_ + c0;
  const float bv = bias[(size_t)e * D_ + c0 + lane];

  // staging geometry (fixed per thread):
  // W op j: elem16 = j*256 + tid -> row = 16*j + (tid>>4), col4 = tid&15
  const int wrow0 = tid >> 4, wc4 = tid & 15;
  // x: elem16 = tid -> slot = tid>>3, r4 = tid&7 (LDS [slot][r] linear)
  const int xslot = tid >> 3, xr4 = tid & 7;

  for (int beg = 0; beg < Ttot; beg += TG) {
    const int T = (Ttot - beg < TG) ? (Ttot - beg) : TG;
    const int xTokRow = toksL[beg + xslot];  // padded slots -> token 0 (safe)
    const bool active = (wv * 8) < T;        // wave-uniform

    float acc[8];
#pragma unroll
    for (int t = 0; t < 8; ++t) acc[t] = 0.f;

#define STAGE(s, b) do {                                                \
    const int _k0 = (s) * BK;                                           \
    GLDS16(tr + (size_t)(_k0 + wrow0) * D_ + wc4 * 4,                   \
           &wl[b][(wv * 64) * 4]);                                      \
    GLDS16(tr + (size_t)(_k0 + 16 + wrow0) * D_ + wc4 * 4,              \
           &wl[b][(256 + wv * 64) * 4]);                                \
    GLDS16(x + ((size_t)xTokRow << 10) + _k0 + xr4 * 4,                 \
           &xs[b][(wv * 64) * 4]);                                      \
  } while (0)

    STAGE(0, 0);
    __syncthreads();  // prologue drain (once per pass)

    for (int s = 0; s < NS; ++s) {
      const int cur = s & 1;
      if (s + 1 < NS) STAGE(s + 1, cur ^ 1);  // prefetch: no reg consumer
      if (active) {
        const float* __restrict__ wb = &wl[cur][0];
        const float* __restrict__ xb = &xs[cur][wv * 8 * BK];
#pragma unroll 1  // keep each scheduling region small: no pressure blowup
        for (int rb = 0; rb < BK / 4; ++rb) {
          const float w0 = wb[(rb * 4 + 0) * CPB + lane];
          const float w1 = wb[(rb * 4 + 1) * CPB + lane];
          const float w2 = wb[(rb * 4 + 2) * CPB + lane];
          const float w3 = wb[(rb * 4 + 3) * CPB + lane];
#pragma unroll
          for (int t = 0; t < 8; ++t) {
            const float4 xv = *(const float4*)&xb[t * BK + rb * 4];
            acc[t] += xv.x * w0 + xv.y * w1 + xv.z * w2 + xv.w * w3;
          }
        }
      }
      __syncthreads();  // single vmcnt drain per step, hidden under compute
    }
#undef STAGE

    // ---- epilogue: bias + tanh + store (no k-reduce needed) ----
    if (active) {
#pragma unroll
      for (int j = 0; j < 8; ++j) {
        const int slot = wv * 8 + j;
        if (slot < T) {
          const int tok = toksL[beg + slot];
          out[((size_t)tok << 10) + c0 + lane] = tanhf(acc[j] + bv);
        }
      }
    }
  }
}

extern "C" void kernel_launch(void* const* d_in, const int* in_sizes, int n_in,
                              void* d_out, int out_size, void* d_ws, size_t ws_size,
                              hipStream_t stream) {
  const float* x     = (const float*)d_in[0];
  const int*   urls  = (const int*)d_in[1];
  const float* trans = (const float*)d_in[2];
  const float* bias  = (const float*)d_in[3];
  float* out = (float*)d_out;

  dim3 grid(CS, E_);
  fused_moe_kernel<<<grid, 256, 0, stream>>>(x, urls, trans, bias, out);
}